// Round 3
// baseline (385.463 us; speedup 1.0000x reference)
//
#include <hip/hip_runtime.h>
#include <hip/hip_bf16.h>
#include <math.h>

// Problem constants (fixed by setup_inputs): B=8, C=16, S=64, HID=32
#define SD   64
#define NC   16
#define NHID 32
#define NB   8
#define ALIVE_T 0.1f
#define LROW 128   // LDS bytes per voxel row (64 bf16 feats; H/dy overlays)

typedef float        f32x4  __attribute__((ext_vector_type(4)));
typedef short        bf16x8 __attribute__((ext_vector_type(8)));
typedef unsigned int u32x2  __attribute__((ext_vector_type(2)));

static __device__ __forceinline__ unsigned short f2bf(float f) {
    return __builtin_bit_cast(unsigned short, __float2bfloat16(f));
}
static __device__ __forceinline__ unsigned pack2(float lo, float hi) {
    return (unsigned)f2bf(lo) | ((unsigned)f2bf(hi) << 16);
}
// XOR-swizzled LDS address: row r0 (0..63), 16B chunk c (0..7), intra byte o.
// chunk ^= (r0&7): every access pattern in this kernel (b128 col-writes,
// b128 row-frag reads, b64 H writes) spreads across 8 phys chunks = 32 banks.
static __device__ __forceinline__ unsigned char* swz(
    unsigned char* lds, int r0, int c, int o) {
    return lds + r0 * LROW + (((c ^ (r0 & 7)) << 4) + o);
}

// Kernel 1: Sobel(separable, wrap) -> MLP (MFMA) -> y = x + dy*upd
// One wave owns one (b,d,h) row; w = lane. Per-wave GEMM pair:
//   D1^T[32hid x 64vox] = W1[32x64] . perc^T[64feat x 64vox]   (16 MFMA)
//   dy^T[16ch x 64vox]  = W2[16x32] . relu(D1^T)               ( 4 MFMA)
// Feature k-order is channel-interleaved: feat = 4*ch + class, so each
// channel-pair's 8 feats = 16B contiguous -> single ds_write_b128 (floor).
// W1's A-frag gather is permuted to match. All LDS is wave-private, XOR
// swizzled (see swz) -> zero barriers, all DS ops at bank floor.
// R2 was latency-bound at 41.8% occupancy (LDS 40KB -> 4 blk/CU) with 16-way
// write conflicts (LSTR=160 => 4 bank phases). This layout: 32KB/block ->
// 5 blk/CU if VGPR<=102; weights/bias loads deferred out of Sobel to fit.
__global__ __launch_bounds__(256, 4) void nca_step(
    const float* __restrict__ x, const float* __restrict__ rm,
    const float* __restrict__ W1, const float* __restrict__ b1,
    const float* __restrict__ W2, float* __restrict__ y,
    float* __restrict__ alpha)
{
    const int tid  = threadIdx.x;
    const int lane = tid & 63;                 // w (voxel within row)
    const int wid  = tid >> 6;
    const int r    = blockIdx.x * 4 + wid;
    const int h    = r & 63;
    const int d    = (r >> 6) & 63;
    const int b    = r >> 12;

    const int lg = lane >> 4;                  // k-group 0..3
    const int ln = lane & 15;                  // row/col within MFMA tile

    __shared__ __align__(16) unsigned char lds_all[4][64 * LROW];
    unsigned char* lds = lds_all[wid];

    // ---- Sobel (fp32, unchanged math); features -> LDS in bf16 ----
    const int dm = (d + 63) & 63, dp = (d + 1) & 63;
    const int hm = (h + 63) & 63, hp = (h + 1) & 63;
    const int lm = (lane + 63) & 63, lp = (lane + 1) & 63;

    const int o_mm = (dm << 12) + (hm << 6) + lane;
    const int o_m0 = (dm << 12) + (h  << 6) + lane;
    const int o_mp = (dm << 12) + (hp << 6) + lane;
    const int o_0m = (d  << 12) + (hm << 6) + lane;
    const int o_00 = (d  << 12) + (h  << 6) + lane;
    const int o_0p = (d  << 12) + (hp << 6) + lane;
    const int o_pm = (dp << 12) + (hm << 6) + lane;
    const int o_p0 = (dp << 12) + (h  << 6) + lane;
    const int o_pp = (dp << 12) + (hp << 6) + lane;

    float xv[NC];   // center x stays fp32 for the exact residual add

    #pragma unroll
    for (int c0 = 0; c0 < NC; c0 += 2) {
        float gxa, gya, gza, xa, gxb, gyb, gzb, xb;
        {
            const float* base = x + (((size_t)(b * NC + c0)) << 18);
            float v_mm = base[o_mm], v_m0 = base[o_m0], v_mp = base[o_mp];
            float v_0m = base[o_0m], v_00 = base[o_00], v_0p = base[o_0p];
            float v_pm = base[o_pm], v_p0 = base[o_p0], v_pp = base[o_pp];
            float am = v_mm + 2.f * v_m0 + v_mp;
            float a0 = v_0m + 2.f * v_00 + v_0p;
            float ap = v_pm + 2.f * v_p0 + v_pp;
            float gm = v_mp - v_mm;
            float g0 = v_0p - v_0m;
            float gp = v_pp - v_pm;
            float P_hh = am + 2.f * a0 + ap;
            float P_hg = gm + 2.f * g0 + gp;
            float P_gh = ap - am;
            gxa = __shfl(P_hh, lp, 64) - __shfl(P_hh, lm, 64);
            gya = __shfl(P_hg, lm, 64) + 2.f * P_hg + __shfl(P_hg, lp, 64);
            gza = __shfl(P_gh, lm, 64) + 2.f * P_gh + __shfl(P_gh, lp, 64);
            xa  = v_00;
        }
        {
            const float* base = x + (((size_t)(b * NC + c0 + 1)) << 18);
            float v_mm = base[o_mm], v_m0 = base[o_m0], v_mp = base[o_mp];
            float v_0m = base[o_0m], v_00 = base[o_00], v_0p = base[o_0p];
            float v_pm = base[o_pm], v_p0 = base[o_p0], v_pp = base[o_pp];
            float am = v_mm + 2.f * v_m0 + v_mp;
            float a0 = v_0m + 2.f * v_00 + v_0p;
            float ap = v_pm + 2.f * v_p0 + v_pp;
            float gm = v_mp - v_mm;
            float g0 = v_0p - v_0m;
            float gp = v_pp - v_pm;
            float P_hh = am + 2.f * a0 + ap;
            float P_hg = gm + 2.f * g0 + gp;
            float P_gh = ap - am;
            gxb = __shfl(P_hh, lp, 64) - __shfl(P_hh, lm, 64);
            gyb = __shfl(P_hg, lm, 64) + 2.f * P_hg + __shfl(P_hg, lp, 64);
            gzb = __shfl(P_gh, lm, 64) + 2.f * P_gh + __shfl(P_gh, lp, 64);
            xb  = v_00;
        }
        xv[c0] = xa; xv[c0 + 1] = xb;
        // feats f = 4*ch + cls; this pair = bytes [8*c0, 8*c0+16) = chunk c0/2
        bf16x8 pk;
        pk[0] = (short)f2bf(gxa); pk[1] = (short)f2bf(gya);
        pk[2] = (short)f2bf(gza); pk[3] = (short)f2bf(xa);
        pk[4] = (short)f2bf(gxb); pk[5] = (short)f2bf(gyb);
        pk[6] = (short)f2bf(gzb); pk[7] = (short)f2bf(xb);
        *(bf16x8*)swz(lds, lane, c0 >> 1, 0) = pk;
    }

    // ---- GEMM1: D1^T = W1 . perc^T (bias added at relu) ----
    // A-frag gather permuted for channel-interleaved k-order:
    // k = ks*32+lg*8+j  ->  W1 col = (j&3)*16 + ks*8 + lg*2 + (j>>2)
    bf16x8 a1[2][2];
    #pragma unroll
    for (int mt = 0; mt < 2; ++mt)
      #pragma unroll
      for (int ks = 0; ks < 2; ++ks) {
        const float* wr = W1 + (ln + 16 * mt) * 64 + ks * 8 + lg * 2;
        bf16x8 f;
        #pragma unroll
        for (int j = 0; j < 8; ++j)
            f[j] = (short)f2bf(wr[(j & 3) * 16 + (j >> 2)]);
        a1[mt][ks] = f;
      }

    f32x4 acc1[2][4];
    #pragma unroll
    for (int nt = 0; nt < 4; ++nt) {
        acc1[0][nt] = (f32x4){0.f, 0.f, 0.f, 0.f};
        acc1[1][nt] = (f32x4){0.f, 0.f, 0.f, 0.f};
    }
    #pragma unroll
    for (int nt = 0; nt < 4; ++nt) {   // per-nt frag load: low VGPR pressure
        bf16x8 bp0 = *(const bf16x8*)swz(lds, ln + 16 * nt, lg,     0);
        bf16x8 bp1 = *(const bf16x8*)swz(lds, ln + 16 * nt, 4 + lg, 0);
        acc1[0][nt] = __builtin_amdgcn_mfma_f32_16x16x32_bf16(a1[0][0], bp0, acc1[0][nt], 0, 0, 0);
        acc1[1][nt] = __builtin_amdgcn_mfma_f32_16x16x32_bf16(a1[1][0], bp0, acc1[1][nt], 0, 0, 0);
        acc1[0][nt] = __builtin_amdgcn_mfma_f32_16x16x32_bf16(a1[0][1], bp1, acc1[0][nt], 0, 0, 0);
        acc1[1][nt] = __builtin_amdgcn_mfma_f32_16x16x32_bf16(a1[1][1], bp1, acc1[1][nt], 0, 0, 0);
    }

    // ---- bias + relu -> bf16 H[vox][hid] overlay (bytes [0,64)) ----
    // lane's regs of tile (mt,nt): hid = lg*4+{0..3}+16mt at vox = ln+16nt
    // -> logical bytes [8lg+32mt, +8) -> chunk 2mt+(lg>>1), intra 8*(lg&1)
    const f32x4 bl = *(const f32x4*)(b1 + lg * 4);
    const f32x4 bh = *(const f32x4*)(b1 + 16 + lg * 4);
    #pragma unroll
    for (int mt = 0; mt < 2; ++mt)
      #pragma unroll
      for (int nt = 0; nt < 4; ++nt) {
        f32x4 v = acc1[mt][nt];
        f32x4 bb = mt ? bh : bl;
        u32x2 u;
        u[0] = pack2(fmaxf(v[0] + bb[0], 0.f), fmaxf(v[1] + bb[1], 0.f));
        u[1] = pack2(fmaxf(v[2] + bb[2], 0.f), fmaxf(v[3] + bb[3], 0.f));
        *(u32x2*)swz(lds, ln + 16 * nt, 2 * mt + (lg >> 1), (lg & 1) * 8) = u;
      }

    // ---- GEMM2: dy^T = W2 . H^T ; dy -> f32 overlay (bytes [64,128)) ----
    bf16x8 a2;
    #pragma unroll
    for (int j = 0; j < 8; ++j)
        a2[j] = (short)f2bf(W2[ln * 32 + lg * 8 + j]);
    #pragma unroll
    for (int nt = 0; nt < 4; ++nt) {
        bf16x8 bhf = *(const bf16x8*)swz(lds, ln + 16 * nt, lg, 0);
        f32x4 acc2 = (f32x4){0.f, 0.f, 0.f, 0.f};
        acc2 = __builtin_amdgcn_mfma_f32_16x16x32_bf16(a2, bhf, acc2, 0, 0, 0);
        *(f32x4*)swz(lds, ln + 16 * nt, 4 + lg, 0) = acc2;  // ch lg*4..+3
    }

    // read back in original lane=vox layout -> coalesced epilogue
    float dyv[NC];
    #pragma unroll
    for (int j = 0; j < 4; ++j) {
        f32x4 t = *(const f32x4*)swz(lds, lane, 4 + j, 0);
        dyv[4 * j + 0] = t[0]; dyv[4 * j + 1] = t[1];
        dyv[4 * j + 2] = t[2]; dyv[4 * j + 3] = t[3];
    }

    // y = x + dy * floor(rm + 0.25); write y, and alpha = y[:,3]
    const size_t voff = ((size_t)d << 12) + ((size_t)h << 6) + lane;
    #pragma unroll
    for (int ch = 0; ch < NC; ++ch) {
        const size_t idx = (((size_t)(b * NC + ch)) << 18) + voff;
        float upd = floorf(rm[idx] + 0.25f);
        float yv  = fmaf(dyv[ch], upd, xv[ch]);
        y[idx] = yv;
        if (ch == 3) alpha[(((size_t)b) << 18) + voff] = yv;
    }
}

// Kernel 2: 3x3x3 max-pool of alpha (-inf borders, NO wrap), then mask.
// alive = (pooled > 0.1); P(dead) ~ 6e-8 for this data -> store zeros only
// where dead (conditional, exec-masked); no y read-modify-write.
__global__ __launch_bounds__(256, 4) void alive_mask(
    const float* __restrict__ alpha, float* __restrict__ y)
{
    const int tid  = blockIdx.x * 256 + threadIdx.x;
    const int lane = threadIdx.x & 63;
    const int wq   = tid & 15;          // which float4 in the row
    const int w4   = wq << 2;
    const int h    = (tid >> 4) & 63;
    const int d    = (tid >> 10) & 63;
    const int b    = tid >> 16;

    const float* ab = alpha + (((size_t)b) << 18);

    float m0 = -INFINITY, m1 = -INFINITY, m2 = -INFINITY, m3 = -INFINITY;
    #pragma unroll
    for (int dz = -1; dz <= 1; ++dz) {
        int dd = d + dz;
        if (dd < 0 || dd > 63) continue;   // -inf border (padding, not wrap)
        #pragma unroll
        for (int hy = -1; hy <= 1; ++hy) {
            int hh = h + hy;
            if (hh < 0 || hh > 63) continue;
            const float4 v = *reinterpret_cast<const float4*>(
                ab + (dd << 12) + (hh << 6) + w4);
            m0 = fmaxf(m0, v.x); m1 = fmaxf(m1, v.y);
            m2 = fmaxf(m2, v.z); m3 = fmaxf(m3, v.w);
        }
    }
    float left  = __shfl(m3, (lane + 63) & 63, 64);
    float right = __shfl(m0, (lane + 1) & 63, 64);
    if (wq == 0)  left  = -INFINITY;
    if (wq == 15) right = -INFINITY;

    float p0 = fmaxf(left, fmaxf(m0, m1));
    float p1 = fmaxf(m0,   fmaxf(m1, m2));
    float p2 = fmaxf(m1,   fmaxf(m2, m3));
    float p3 = fmaxf(m2,   fmaxf(m3, right));

    const bool d0 = !(p0 > ALIVE_T);
    const bool d1 = !(p1 > ALIVE_T);
    const bool d2 = !(p2 > ALIVE_T);
    const bool d3 = !(p3 > ALIVE_T);

    if (d0 | d1 | d2 | d3) {               // ~never taken; exec-mask skip
        const size_t voff = ((size_t)d << 12) + ((size_t)h << 6) + w4;
        #pragma unroll
        for (int ch = 0; ch < NC; ++ch) {
            float* p = y + (((size_t)(b * NC + ch)) << 18) + voff;
            if (d0) p[0] = 0.f;
            if (d1) p[1] = 0.f;
            if (d2) p[2] = 0.f;
            if (d3) p[3] = 0.f;
        }
    }
}

extern "C" void kernel_launch(void* const* d_in, const int* in_sizes, int n_in,
                              void* d_out, int out_size, void* d_ws, size_t ws_size,
                              hipStream_t stream) {
    const float* x  = (const float*)d_in[0];
    const float* rm = (const float*)d_in[1];
    const float* W1 = (const float*)d_in[2];
    const float* b1 = (const float*)d_in[3];
    const float* W2 = (const float*)d_in[4];
    float* y     = (float*)d_out;
    float* alpha = (float*)d_ws;   // 8 * 64^3 * 4 = 8 MB scratch

    const int rows    = NB * SD * SD;       // 32768 (b,d,h) rows
    const int blocks1 = rows / 4;           // 4 waves (rows) per block
    const int blocks2 = (NB * SD * SD * 16) / 256;  // 4 voxels per thread

    nca_step<<<blocks1, 256, 0, stream>>>(x, rm, W1, b1, W2, y, alpha);
    alive_mask<<<blocks2, 256, 0, stream>>>(alpha, y);
}